// Round 5
// baseline (164.434 us; speedup 1.0000x reference)
//
#include <hip/hip_runtime.h>
#include <cstdint>
#include <cmath>

// ---------------------------------------------------------------------------
// MHKPattLayer fused kernel for MI355X (gfx950) — round 5
//   QBLK=64, 1024 threads (16 waves), 1 block/CU.
//   P1: 3-pass bf16-split QK^T with 1-stage register prefetch of K frags.
//   P2: f32 l2norm + GELU (A&S 7.1.28) + mean.
//   P4: PV on all 16 waves: (qt2, vt2 64-wide, nh n-quarter), 2 accumulators,
//       V prefetch 1 step ahead, LDS blob reduction across nh.
// B=4, T=2048, C=1024, H=8, N=1024, Dk=Dv=128
// ---------------------------------------------------------------------------

typedef __bf16 bf16x8 __attribute__((ext_vector_type(8)));
typedef float  f32x16 __attribute__((ext_vector_type(16)));
typedef unsigned short u16x8 __attribute__((ext_vector_type(8)));

__device__ __forceinline__ unsigned short bfbits(__bf16 b) {
  return __builtin_bit_cast(unsigned short, b);
}

// exact GELU, scale pre-folded: g = gelu(raw*scale), c707 = scale/sqrt(2),
// chalf = scale*0.5.  erf via A&S 7.1.28: 1-(1+a1 x..a6 x^6)^-16, |eps|<=3e-7.
__device__ __forceinline__ float gelu_s(float raw, float c707, float chalf) {
  const float s = raw * c707;
  const float a = fabsf(s);
  float u = fmaf(a, 4.30638e-5f, 2.765672e-4f);
  u = fmaf(u, a, 1.520143e-4f);
  u = fmaf(u, a, 9.2705272e-3f);
  u = fmaf(u, a, 4.22820123e-2f);
  u = fmaf(u, a, 7.05230784e-2f);
  u = fmaf(u, a, 1.0f);
  const float r  = __builtin_amdgcn_rcpf(u);   // u >= 1 always
  const float r2 = r * r;
  const float r4 = r2 * r2;
  const float r8 = r4 * r4;
  const float r16 = r8 * r8;
  const float er = copysignf(1.0f - r16, s);
  const float hf = raw * chalf;
  return fmaf(hf, er, hf);
}

// ---------------- fused prep kernel ----------------
// first 131072 threads: K -> hi/lo bf16 frag-packed [h][kc=16][n=1024][e=8]
// next  131072 threads: V -> bf16 frag-packed      [h][s2=128][v=128][e=8]
__global__ void prep_kv(const float* __restrict__ key,
                        const float* __restrict__ val,
                        unsigned short* __restrict__ kh,
                        unsigned short* __restrict__ kl,
                        unsigned short* __restrict__ vp) {
  const int gid = blockIdx.x * 256 + threadIdx.x;   // 0..262143
  if (gid < 131072) {
    const int h  = gid >> 14;
    const int kc = (gid >> 10) & 15;
    const int n  = gid & 1023;
    const float* src = key + ((size_t)(h << 10) + n) * 128 + kc * 8;
    const float4 f0 = *(const float4*)src;
    const float4 f1 = *(const float4*)(src + 4);
    const float fv[8] = {f0.x, f0.y, f0.z, f0.w, f1.x, f1.y, f1.z, f1.w};
    u16x8 hv, lv;
#pragma unroll
    for (int e = 0; e < 8; ++e) {
      const __bf16 hb = (__bf16)fv[e];
      hv[e] = bfbits(hb);
      lv[e] = bfbits((__bf16)(fv[e] - (float)hb));
    }
    const size_t o = ((size_t)(h * 16 + kc) * 1024 + n) * 8;
    *(u16x8*)(kh + o) = hv;
    *(u16x8*)(kl + o) = lv;
  } else {
    const int tid = gid - 131072;
    const int h   = tid >> 14;
    const int s2  = (tid >> 7) & 127;
    const int v   = tid & 127;
    const float* src = val + ((size_t)(h << 10) + s2 * 8) * 128 + v;
    u16x8 ov;
#pragma unroll
    for (int e = 0; e < 8; ++e) ov[e] = bfbits((__bf16)src[(size_t)e * 128]);
    *(u16x8*)(vp + ((size_t)(h * 128 + s2) * 128 + v) * 8) = ov;
  }
}

// ---------------- fused kernel ----------------
// grid 1024 (h = bid&7 -> one head per XCD), 1024 threads (16 waves)
// LDS map (bytes):
//   [0, 131072)      S bf16, frag-major granules: slot = ng*64 + (q ^ (ng&7)),
//                    ng = n/8 (0..127), q = 0..63; 16B per granule.
//                    Aliased in phases 0-1: Q-hi [0,16384), Q-lo [16384,32768).
//                    Aliased in phase 4 tail: partial blobs
//                    nh*32768 + job*8192 + lane*128 (rotated 16B chunks).
//   [131072, 135168) red1 (16 waves x 64 q, f32)
//   [135168, 139264) red2
#define RED1   131072
#define RED2   135168
#define SMEMSZ 139264

__global__ __launch_bounds__(1024, 4) void fused_mhk(
    const float* __restrict__ x,
    const unsigned short* __restrict__ k_hi,
    const unsigned short* __restrict__ k_lo,
    const unsigned short* __restrict__ v_pk,
    float* __restrict__ out)
{
  extern __shared__ char smem[];
  const int tid  = threadIdx.x;
  const int wave = tid >> 6;      // 0..15
  const int lane = tid & 63;
  const int l31  = lane & 31;
  const int hi   = lane >> 5;

  const int bid = blockIdx.x;
  const int h   = bid & 7;        // head fixed per XCD slot
  const int g8  = bid >> 3;       // 0..127
  const int b   = g8 & 3;
  const int tt  = g8 >> 2;        // 0..31
  const int t0  = tt * 64;

  // ---- Phase 0: load Q tile [64][128] fp32, split hi/lo bf16 -> LDS (swizzled)
  {
    const float* xq = x + ((size_t)(b * 2048 + t0)) * 1024 + h * 128;
    const int r  = tid >> 4;      // 0..63 (q row)
    const int kc = tid & 15;      // 8-elem k chunk
    const float* sp = xq + (size_t)r * 1024 + kc * 8;
    const float4 f0 = *(const float4*)sp;
    const float4 f1 = *(const float4*)(sp + 4);
    const float fv[8] = {f0.x, f0.y, f0.z, f0.w, f1.x, f1.y, f1.z, f1.w};
    bf16x8 hv; u16x8 lv;
#pragma unroll
    for (int e = 0; e < 8; ++e) {
      const __bf16 hb = (__bf16)fv[e];
      hv[e] = hb;
      lv[e] = bfbits((__bf16)(fv[e] - (float)hb));
    }
    const int g = kc * 64 + (r ^ ((kc >> 1) & 7));
    *(bf16x8*)(smem + g * 16) = hv;
    *(u16x8*)(smem + 16384 + g * 16) = lv;
  }

  // K fragment pointers; prefetch s=0 BEFORE the barrier (latency hidden
  // under Q staging + barrier drain).
  const unsigned short* kph = k_hi + (size_t)h * 131072;
  const unsigned short* kpl = k_lo + (size_t)h * 131072;
  const size_t kb = (size_t)hi * 8192 + (size_t)(wave * 64 + l31) * 8;
  bf16x8 kch0 = *(const bf16x8*)(kph + kb);
  bf16x8 kch1 = *(const bf16x8*)(kph + kb + 256);
  bf16x8 kcl0 = *(const bf16x8*)(kpl + kb);
  bf16x8 kcl1 = *(const bf16x8*)(kpl + kb + 256);

  __syncthreads();

  // ---- Phase 1: swapped QK^T with 1-stage K prefetch.
  //      acc[t][qt]: lane holds q = qt*32+l31, n = wave*64+t*32+crow(r,hi)
  f32x16 acc[2][2];
#pragma unroll
  for (int t = 0; t < 2; ++t)
#pragma unroll
    for (int qt = 0; qt < 2; ++qt)
#pragma unroll
      for (int i = 0; i < 16; ++i) acc[t][qt][i] = 0.f;

  {
    const int hi64 = hi * 64;
#pragma unroll
    for (int s = 0; s < 8; ++s) {
      // prefetch next step's K fragments (registers, no LDS dependency)
      bf16x8 knh0, knh1, knl0, knl1;
      if (s < 7) {
        const unsigned short* kah = kph + kb + (s + 1) * 16384;
        const unsigned short* kal = kpl + kb + (s + 1) * 16384;
        knh0 = *(const bf16x8*)(kah);
        knh1 = *(const bf16x8*)(kah + 256);
        knl0 = *(const bf16x8*)(kal);
        knl1 = *(const bf16x8*)(kal + 256);
      }
      // Q fragments for this step
      const int gx0 = (2 * s) * 64 + hi64 + (l31 ^ s);
      const int gx1 = (2 * s) * 64 + hi64 + ((32 + l31) ^ s);
      const bf16x8 bqh0 = *(const bf16x8*)(smem + gx0 * 16);
      const bf16x8 bql0 = *(const bf16x8*)(smem + 16384 + gx0 * 16);
      const bf16x8 bqh1 = *(const bf16x8*)(smem + gx1 * 16);
      const bf16x8 bql1 = *(const bf16x8*)(smem + 16384 + gx1 * 16);

      acc[0][0] = __builtin_amdgcn_mfma_f32_32x32x16_bf16(kch0, bqh0, acc[0][0], 0, 0, 0);
      acc[0][1] = __builtin_amdgcn_mfma_f32_32x32x16_bf16(kch0, bqh1, acc[0][1], 0, 0, 0);
      acc[0][0] = __builtin_amdgcn_mfma_f32_32x32x16_bf16(kch0, bql0, acc[0][0], 0, 0, 0);
      acc[0][1] = __builtin_amdgcn_mfma_f32_32x32x16_bf16(kch0, bql1, acc[0][1], 0, 0, 0);
      acc[0][0] = __builtin_amdgcn_mfma_f32_32x32x16_bf16(kcl0, bqh0, acc[0][0], 0, 0, 0);
      acc[0][1] = __builtin_amdgcn_mfma_f32_32x32x16_bf16(kcl0, bqh1, acc[0][1], 0, 0, 0);
      acc[1][0] = __builtin_amdgcn_mfma_f32_32x32x16_bf16(kch1, bqh0, acc[1][0], 0, 0, 0);
      acc[1][1] = __builtin_amdgcn_mfma_f32_32x32x16_bf16(kch1, bqh1, acc[1][1], 0, 0, 0);
      acc[1][0] = __builtin_amdgcn_mfma_f32_32x32x16_bf16(kch1, bql0, acc[1][0], 0, 0, 0);
      acc[1][1] = __builtin_amdgcn_mfma_f32_32x32x16_bf16(kch1, bql1, acc[1][1], 0, 0, 0);
      acc[1][0] = __builtin_amdgcn_mfma_f32_32x32x16_bf16(kcl1, bqh0, acc[1][0], 0, 0, 0);
      acc[1][1] = __builtin_amdgcn_mfma_f32_32x32x16_bf16(kcl1, bqh1, acc[1][1], 0, 0, 0);

      if (s < 7) { kch0 = knh0; kch1 = knh1; kcl0 = knl0; kcl1 = knl1; }
    }
  }

  // ---- Phase 2: l2-norm -> scale -> GELU -> mean (per q-row)
  float* red1 = (float*)(smem + RED1);
  float* red2 = (float*)(smem + RED2);

  float ss0 = 0.f, ss1 = 0.f;
#pragma unroll
  for (int t = 0; t < 2; ++t)
#pragma unroll
    for (int i = 0; i < 16; ++i) {
      ss0 += acc[t][0][i] * acc[t][0][i];
      ss1 += acc[t][1][i] * acc[t][1][i];
    }
  ss0 += __shfl_xor(ss0, 32);
  ss1 += __shfl_xor(ss1, 32);
  red1[wave * 64 + lane] = hi ? ss1 : ss0;
  __syncthreads();
  float sum0 = 0.f, sum1 = 0.f;
#pragma unroll
  for (int w = 0; w < 16; ++w) {
    sum0 += red1[w * 64 + l31];
    sum1 += red1[w * 64 + 32 + l31];
  }
  const float scale0 = 32.0f / fmaxf(sqrtf(sum0), 1e-8f);
  const float scale1 = 32.0f / fmaxf(sqrtf(sum1), 1e-8f);
  const float c707_0 = scale0 * 0.70710678118654752f;
  const float c707_1 = scale1 * 0.70710678118654752f;
  const float chalf0 = scale0 * 0.5f;
  const float chalf1 = scale1 * 0.5f;

  float gs0 = 0.f, gs1 = 0.f;
#pragma unroll
  for (int t = 0; t < 2; ++t)
#pragma unroll
    for (int i = 0; i < 16; ++i) {
      const float g0 = gelu_s(acc[t][0][i], c707_0, chalf0);
      acc[t][0][i] = g0; gs0 += g0;
      const float g1 = gelu_s(acc[t][1][i], c707_1, chalf1);
      acc[t][1][i] = g1; gs1 += g1;
    }
  gs0 += __shfl_xor(gs0, 32);
  gs1 += __shfl_xor(gs1, 32);
  red2[wave * 64 + lane] = hi ? gs1 : gs0;
  __syncthreads();
  float mean0 = 0.f, mean1 = 0.f;
#pragma unroll
  for (int w = 0; w < 16; ++w) {
    mean0 += red2[w * 64 + l31];
    mean1 += red2[w * 64 + 32 + l31];
  }
  mean0 *= (1.0f / 1024.0f);
  mean1 *= (1.0f / 1024.0f);

  // P4 job mapping (needed early for V prefetch)
  const int qt2 = wave & 1;          // q-tile (32 rows)
  const int vt2 = (wave >> 1) & 1;   // 64-wide v-tile
  const int nh  = wave >> 2;         // 0..3, 256-n slice
  const unsigned short* vbase = v_pk + (size_t)h * 131072;
  const int vc0 = (vt2 * 64 + l31) * 8;

  // Issue first V fragments now — latency hides under the pack phase.
  const int ng00 = nh * 32 + hi;
  bf16x8 v0 = *(const bf16x8*)(vbase + (size_t)ng00 * 1024 + vc0);
  bf16x8 v1 = *(const bf16x8*)(vbase + (size_t)ng00 * 1024 + vc0 + 256);

  // ---- Phase 3: mask (strict >) + bf16 pack -> S frag-major granules in LDS
#pragma unroll
  for (int t = 0; t < 2; ++t) {
#pragma unroll
    for (int qt = 0; qt < 2; ++qt) {
      const float mn = qt ? mean1 : mean0;
      const int q = qt * 32 + l31;
#pragma unroll
      for (int gi = 0; gi < 4; ++gi) {
        float g0 = acc[t][qt][4 * gi + 0]; g0 = (g0 > mn) ? g0 : 0.f;
        float g1 = acc[t][qt][4 * gi + 1]; g1 = (g1 > mn) ? g1 : 0.f;
        float g2 = acc[t][qt][4 * gi + 2]; g2 = (g2 > mn) ? g2 : 0.f;
        float g3 = acc[t][qt][4 * gi + 3]; g3 = (g3 > mn) ? g3 : 0.f;
        uint2 pk;
        pk.x = (unsigned)bfbits((__bf16)g0) | ((unsigned)bfbits((__bf16)g1) << 16);
        pk.y = (unsigned)bfbits((__bf16)g2) | ((unsigned)bfbits((__bf16)g3) << 16);
        const int ng = wave * 8 + t * 4 + gi;
        const int swz = (t * 4 + gi) & 7;               // = ng & 7
        *(uint2*)(smem + (ng * 64 + (q ^ swz)) * 16 + hi * 8) = pk;
      }
    }
  }
  __syncthreads();

  // ---- Phase 4: PV. wave (qt2, vt2, nh): 32q x 64v over n = nh*256..+256.
  //      16 steps: 1 S ds_read_b128 -> 2 MFMA (independent accumulators),
  //      V prefetched 1 step ahead.
  f32x16 o0, o1;
#pragma unroll
  for (int i = 0; i < 16; ++i) { o0[i] = 0.f; o1[i] = 0.f; }

  const int qrow = qt2 * 32 + l31;
#pragma unroll
  for (int ks = 0; ks < 16; ++ks) {
    const int ng = nh * 32 + ks * 2 + hi;
    const bf16x8 aa = *(const bf16x8*)(smem + (ng * 64 + (qrow ^ (ng & 7))) * 16);
    bf16x8 p0, p1;
    if (ks < 15) {
      p0 = *(const bf16x8*)(vbase + (size_t)(ng + 2) * 1024 + vc0);
      p1 = *(const bf16x8*)(vbase + (size_t)(ng + 2) * 1024 + vc0 + 256);
    }
    o0 = __builtin_amdgcn_mfma_f32_32x32x16_bf16(aa, v0, o0, 0, 0, 0);
    o1 = __builtin_amdgcn_mfma_f32_32x32x16_bf16(aa, v1, o1, 0, 0, 0);
    if (ks < 15) { v0 = p0; v1 = p1; }
  }
  __syncthreads();   // all S reads complete; S region reusable for blobs

  // ---- Phase 5: reduce partials across nh via LDS blobs.
  // blob(nh, job=wave&3): base = nh*32768 + job*8192 + lane*128,
  // 8 chunks of 16B, chunk c stored at ((c+lane)&7)*16 (bank spread).
  if (nh != 0) {
    const int bb = nh * 32768 + (wave & 3) * 8192 + lane * 128;
#pragma unroll
    for (int c = 0; c < 8; ++c) {
      const int cc = ((c + lane) & 7) * 16;
      float4 ch;
      if (c < 4) ch = make_float4(o0[4*c], o0[4*c+1], o0[4*c+2], o0[4*c+3]);
      else       ch = make_float4(o1[4*(c-4)], o1[4*(c-4)+1], o1[4*(c-4)+2], o1[4*(c-4)+3]);
      *(float4*)(smem + bb + cc) = ch;
    }
  }
  __syncthreads();
  if (nh != 0) return;

#pragma unroll
  for (int src = 1; src < 4; ++src) {
    const int bb = src * 32768 + (wave & 3) * 8192 + lane * 128;
#pragma unroll
    for (int c = 0; c < 8; ++c) {
      const int cc = ((c + lane) & 7) * 16;
      const float4 ch = *(const float4*)(smem + bb + cc);
      if (c < 4) {
        o0[4*c] += ch.x; o0[4*c+1] += ch.y; o0[4*c+2] += ch.z; o0[4*c+3] += ch.w;
      } else {
        o1[4*(c-4)] += ch.x; o1[4*(c-4)+1] += ch.y;
        o1[4*(c-4)+2] += ch.z; o1[4*(c-4)+3] += ch.w;
      }
    }
  }

  // C/D 32x32: col = l31 (v), row = crow(r,hi)
  float* op = out + ((size_t)(b * 2048 + t0 + qt2 * 32)) * 1024 +
              h * 128 + vt2 * 64 + l31;
#pragma unroll
  for (int r = 0; r < 16; ++r) {
    const int qr = (r & 3) + 8 * (r >> 2) + 4 * hi;
    op[(size_t)qr * 1024]      = o0[r];
    op[(size_t)qr * 1024 + 32] = o1[r];
  }
}

// ---------------- launch ----------------

extern "C" void kernel_launch(void* const* d_in, const int* in_sizes, int n_in,
                              void* d_out, int out_size, void* d_ws, size_t ws_size,
                              hipStream_t stream) {
  const float* x   = (const float*)d_in[0];  // [4][2048][1024]
  const float* key = (const float*)d_in[1];  // [8][1024][128]
  const float* val = (const float*)d_in[2];  // [8][1024][128]
  float* out = (float*)d_out;                // [4][2048][1024]

  if (ws_size < (size_t)6 * 1024 * 1024) return;  // need 6 MB scratch

  unsigned short* k_hi = (unsigned short*)d_ws;   // 1M bf16 (2 MB)
  unsigned short* k_lo = k_hi + 1048576;          // 1M bf16
  unsigned short* v_pk = k_lo + 1048576;          // 1M bf16 (frag-packed V)

  prep_kv<<<dim3(1024), dim3(256), 0, stream>>>(key, val, k_hi, k_lo, v_pk);
  fused_mhk<<<dim3(1024), dim3(1024), SMEMSZ, stream>>>(x, k_hi, k_lo, v_pk, out);
}